// Round 13
// baseline (294.784 us; speedup 1.0000x reference)
//
#include <hip/hip_runtime.h>
#include <math.h>

#define NODES 8192
#define NEDGE 262144
#define DIM 256

typedef float f32x16 __attribute__((ext_vector_type(16)));
typedef _Float16 f16x8 __attribute__((ext_vector_type(8)));
typedef unsigned short u16;
typedef u16 u16x8 __attribute__((ext_vector_type(8)));
typedef u16 u16x4 __attribute__((ext_vector_type(4)));
typedef u16 u16x2 __attribute__((ext_vector_type(2)));

__device__ __forceinline__ float fast_tanh(float x) {
    float t = __expf(2.f * x);
    return 1.f - 2.f * __builtin_amdgcn_rcpf(t + 1.f);
}

__device__ __forceinline__ u16 h_bits(_Float16 h) {
    u16 r; __builtin_memcpy(&r, &h, 2); return r;
}

// ---------------- CSR build (dst-indexed) ----------------
__global__ void k_deg(const int* __restrict__ dst, int* __restrict__ deg) {
    int e = blockIdx.x * blockDim.x + threadIdx.x;
    if (e < NEDGE) atomicAdd(&deg[dst[e]], 1);
}

__global__ void k_scan(const int* __restrict__ deg, int* __restrict__ rowptr,
                       int* __restrict__ cursor) {
    __shared__ int part[256];
    int t = threadIdx.x;
    int base = t * 32;
    int local[32];
    int s = 0;
    for (int i = 0; i < 32; ++i) { local[i] = s; s += deg[base + i]; }
    part[t] = s;
    __syncthreads();
    for (int off = 1; off < 256; off <<= 1) {
        int v = (t >= off) ? part[t - off] : 0;
        __syncthreads();
        part[t] += v;
        __syncthreads();
    }
    int excl = (t == 0) ? 0 : part[t - 1];
    for (int i = 0; i < 32; ++i) {
        int v = excl + local[i];
        rowptr[base + i] = v;
        cursor[base + i] = v;
    }
    if (t == 255) rowptr[NODES] = part[255];
}

__global__ void k_fill(const int* __restrict__ src, const int* __restrict__ dst,
                       int* __restrict__ cursor, int2* __restrict__ sdg) {
    int e = blockIdx.x * blockDim.x + threadIdx.x;
    if (e < NEDGE) {
        int pos = atomicAdd(&cursor[dst[e]], 1);
        sdg[pos] = make_int2(src[e], dst[e]);
    }
}

// ---------------- att_w -> fp16 2-plane fragment order ----------------
__global__ void k_wfrag(const float* __restrict__ W, u16* __restrict__ wf) {
    int t = blockIdx.x * blockDim.x + threadIdx.x;
    if (t >= 16 * 4 * 2 * 64) return;
    int lane = t & 63;
    int mt = (t >> 6) & 1;
    int w = (t >> 7) & 3;
    int gks = t >> 9;
    int row = w * 64 + mt * 32 + (lane & 31);
    int k0 = gks * 16 + (lane >> 5) * 8;
    const float* p = W + (size_t)row * DIM + k0;
    u16x8 v1, v2;
#pragma unroll
    for (int j = 0; j < 8; ++j) {
        float f = p[j];
        _Float16 h1 = (_Float16)f;
        _Float16 h2 = (_Float16)((f - (float)h1) * 2048.f);
        v1[j] = h_bits(h1);
        v2[j] = h_bits(h2);
    }
    size_t base = ((size_t)(gks * 4 + w) * 4 + mt * 2) * 512 + lane * 8;
    *(u16x8*)(wf + base)       = v1;
    *(u16x8*)(wf + base + 512) = v2;
}

// ---------------- [pwa_w ; pwo_w] -> fragment order, K=512 (gks 0..31) -----
__global__ void k_wfrag2(const float* __restrict__ Wa, const float* __restrict__ Wo,
                         u16* __restrict__ wf2) {
    int t = blockIdx.x * blockDim.x + threadIdx.x;
    if (t >= 32 * 4 * 2 * 64) return;
    int lane = t & 63;
    int mt = (t >> 6) & 1;
    int w = (t >> 7) & 3;
    int gks = t >> 9;                       // 0..31
    const float* W = (gks < 16) ? Wa : Wo;
    int row = w * 64 + mt * 32 + (lane & 31);
    int k0 = (gks & 15) * 16 + (lane >> 5) * 8;
    const float* p = W + (size_t)row * DIM + k0;
    u16x8 v1, v2;
#pragma unroll
    for (int j = 0; j < 8; ++j) {
        float f = p[j];
        _Float16 h1 = (_Float16)f;
        _Float16 h2 = (_Float16)((f - (float)h1) * 2048.f);
        v1[j] = h_bits(h1);
        v2[j] = h_bits(h2);
    }
    size_t base = ((size_t)(gks * 4 + w) * 4 + mt * 2) * 512 + lane * 8;
    *(u16x8*)(wf2 + base)       = v1;
    *(u16x8*)(wf2 + base + 512) = v2;
}

// ---------------- alpha, v13: producer/consumer wave specialization --------
// 512 thr: waves 0-3 consume (MFMA, 64 outs each), waves 4-7 produce
// (gather+split+LDS). 4 tiles x 64 edges, K in 2 phases of 128, dbuf 64 KB.
// Per-wave alpha partials to global (apart[w][e]); k_asum reduces.
__global__ __launch_bounds__(512, 2) void k_alpha_v13(
    const float* __restrict__ x, const int2* __restrict__ sdg,
    const u16* __restrict__ wf, const float* __restrict__ bias,
    const float* __restrict__ amap, float* __restrict__ apart)
{
    __shared__ u16 buf[2][2][64][128];   // [phase-buf][plane][edge][128k] = 64 KB
    const int tid = threadIdx.x;
    const int wid = tid >> 6;
    const int lane = tid & 63;
    const int bid = blockIdx.x;
    const int wg = (bid & 7) * 128 + (bid >> 3);   // XCD swizzle, 1024 % 8 == 0
    const int e0 = wg * 256;

    if (wid >= 4) {
        // ================= producer =================
        const int pw = wid - 4;
#define STAGE(T, PH, B) { \
    _Pragma("unroll") for (int i_ = 0; i_ < 16; ++i_) { \
        const int le_ = pw * 16 + i_; \
        int2 sd_ = sdg[e0 + (T) * 64 + le_]; \
        float2 av_ = *(const float2*)(x + (size_t)sd_.x * DIM + (PH) * 128 + lane * 2); \
        float2 bv_ = *(const float2*)(x + (size_t)sd_.y * DIM + (PH) * 128 + lane * 2); \
        float p0_ = av_.x * bv_.x, p1_ = av_.y * bv_.y; \
        _Float16 h10_ = (_Float16)p0_, h11_ = (_Float16)p1_; \
        _Float16 h20_ = (_Float16)((p0_ - (float)h10_) * 2048.f); \
        _Float16 h21_ = (_Float16)((p1_ - (float)h11_) * 2048.f); \
        u16x2 v1_, v2_; \
        v1_[0] = h_bits(h10_); v1_[1] = h_bits(h11_); \
        v2_[0] = h_bits(h20_); v2_[1] = h_bits(h21_); \
        const unsigned off_ = ((unsigned)(lane * 4)) ^ (((unsigned)(le_ & 7)) << 4); \
        *(u16x2*)((char*)&buf[(B)][0][le_][0] + off_) = v1_; \
        *(u16x2*)((char*)&buf[(B)][1][le_][0] + off_) = v2_; } }

        STAGE(0, 0, 0) __syncthreads();
        STAGE(0, 1, 1) __syncthreads();
        STAGE(1, 0, 0) __syncthreads();
        STAGE(1, 1, 1) __syncthreads();
        STAGE(2, 0, 0) __syncthreads();
        STAGE(2, 1, 1) __syncthreads();
        STAGE(3, 0, 0) __syncthreads();
        STAGE(3, 1, 1) __syncthreads();
        __syncthreads();   // final segment (consumers' last mfma+epi)
#undef STAGE
    } else {
        // ================= consumer =================
        const int w = wid;
        const int l31 = lane & 31;
        const int g2 = lane >> 5;
        const unsigned swz = ((unsigned)(l31 & 7)) << 4;

        f32x16 accM[2][2], accC[2][2];
#pragma unroll
        for (int mt = 0; mt < 2; ++mt)
#pragma unroll
            for (int nt = 0; nt < 2; ++nt) { accM[mt][nt] = (f32x16)0.f; accC[mt][nt] = (f32x16)0.f; }

        f16x8 afA[2][2], afB[2][2], afC[2][2];

#define PREFA(DST, GKS) { \
    const u16* pb_ = wf + ((size_t)((GKS) * 4 + w) * 4) * 512 + lane * 8; \
    _Pragma("unroll") for (int mt_ = 0; mt_ < 2; ++mt_) \
    _Pragma("unroll") for (int pl_ = 0; pl_ < 2; ++pl_) \
        DST[mt_][pl_] = *(const f16x8*)(const void*)(pb_ + (mt_ * 2 + pl_) * 512); }

// LKS: k-step within phase (0..7); GA: A index (0..15); B: LDS buf; USE/PF: reg bufs
#define KS(LKS, GA, B, USE, PF) { \
    PREFA(PF, ((GA) + 2) & 15) \
    f16x8 bfr[2][2]; \
    _Pragma("unroll") for (int nt_ = 0; nt_ < 2; ++nt_) { \
        const int en_ = nt_ * 32 + l31; \
        const unsigned off_ = ((unsigned)((LKS) * 32 + g2 * 16)) ^ swz; \
        _Pragma("unroll") for (int pl_ = 0; pl_ < 2; ++pl_) \
            bfr[nt_][pl_] = *(const f16x8*)(const void*)((const char*)&buf[(B)][pl_][en_][0] + off_); \
    } \
    _Pragma("unroll") for (int mt_ = 0; mt_ < 2; ++mt_) \
    _Pragma("unroll") for (int nt_ = 0; nt_ < 2; ++nt_) { \
        accM[mt_][nt_] = __builtin_amdgcn_mfma_f32_32x32x16_f16(USE[mt_][0], bfr[nt_][0], accM[mt_][nt_], 0, 0, 0); \
        accC[mt_][nt_] = __builtin_amdgcn_mfma_f32_32x32x16_f16(USE[mt_][0], bfr[nt_][1], accC[mt_][nt_], 0, 0, 0); \
        accC[mt_][nt_] = __builtin_amdgcn_mfma_f32_32x32x16_f16(USE[mt_][1], bfr[nt_][0], accC[mt_][nt_], 0, 0, 0); } }

// 8 k-steps of one phase; X,Y,Z = A-reg rotation order for this phase's first step
#define PH8(B, G, X, Y, Z) \
    KS(0,(G)+0,B,X,Z) KS(1,(G)+1,B,Y,X) KS(2,(G)+2,B,Z,Y) KS(3,(G)+3,B,X,Z) \
    KS(4,(G)+4,B,Y,X) KS(5,(G)+5,B,Z,Y) KS(6,(G)+6,B,X,Z) KS(7,(G)+7,B,Y,X)

#define EPI(T) { \
    float part0 = 0.f, part1 = 0.f; \
    _Pragma("unroll") for (int mt_ = 0; mt_ < 2; ++mt_) \
    _Pragma("unroll") for (int r_ = 0; r_ < 16; ++r_) { \
        int o_ = 64 * w + 32 * mt_ + (r_ & 3) + 8 * (r_ >> 2) + 4 * g2; \
        float bo_ = bias[o_], ao_ = amap[o_]; \
        float h0_ = accM[mt_][0][r_] + accC[mt_][0][r_] * 4.8828125e-4f; \
        float h1_ = accM[mt_][1][r_] + accC[mt_][1][r_] * 4.8828125e-4f; \
        part0 += ao_ * fast_tanh(h0_ + bo_); \
        part1 += ao_ * fast_tanh(h1_ + bo_); \
    } \
    part0 += __shfl_xor(part0, 32); \
    part1 += __shfl_xor(part1, 32); \
    if (lane < 32) { \
        apart[(size_t)w * NEDGE + e0 + (T) * 64 + lane] = part0; \
        apart[(size_t)w * NEDGE + e0 + (T) * 64 + 32 + lane] = part1; \
    } \
    _Pragma("unroll") for (int mt_ = 0; mt_ < 2; ++mt_) \
    _Pragma("unroll") for (int nt_ = 0; nt_ < 2; ++nt_) { accM[mt_][nt_] = (f32x16)0.f; accC[mt_][nt_] = (f32x16)0.f; } }

        PREFA(afA, 0)
        PREFA(afB, 1)
        __syncthreads();                 // buf0 (t0,ph0) ready
        // tile 0
        PH8(0, 0, afA, afB, afC) __syncthreads();
        PH8(1, 8, afC, afA, afB) EPI(0) __syncthreads();
        // tile 1
        PH8(0, 0, afB, afC, afA) __syncthreads();
        PH8(1, 8, afA, afB, afC) EPI(1) __syncthreads();
        // tile 2
        PH8(0, 0, afC, afA, afB) __syncthreads();
        PH8(1, 8, afB, afC, afA) EPI(2) __syncthreads();
        // tile 3
        PH8(0, 0, afA, afB, afC) __syncthreads();
        PH8(1, 8, afC, afA, afB) EPI(3) __syncthreads();
#undef PREFA
#undef KS
#undef PH8
#undef EPI
    }
}

// ---------------- alpha = sum of 4 per-wave partials (fixed order) ----------
__global__ void k_asum(const float* __restrict__ apart, float* __restrict__ alpha) {
    int i = blockIdx.x * blockDim.x + threadIdx.x;
    alpha[i] = ((apart[i] + apart[NEDGE + i]) + apart[2 * NEDGE + i]) + apart[3 * NEDGE + i];
}

// ---------------- segment softmax + weighted aggregate (unroll-4) ----------
__global__ void k_aggregate(
    const float* __restrict__ x, const float* __restrict__ alpha_pos,
    const int* __restrict__ rowptr, const int2* __restrict__ sdg,
    float* __restrict__ agg)
{
    int gw = (blockIdx.x * blockDim.x + threadIdx.x) >> 6;
    int lane = threadIdx.x & 63;
    if (gw >= NODES) return;
    int start = rowptr[gw], end = rowptr[gw + 1];
    int deg = end - start;
    float m = -INFINITY;
    for (int i = lane; i < deg; i += 64) m = fmaxf(m, alpha_pos[start + i]);
#pragma unroll
    for (int off = 32; off > 0; off >>= 1) m = fmaxf(m, __shfl_xor(m, off));
    float ssum = 0.f;
    for (int i = lane; i < deg; i += 64) ssum += expf(alpha_pos[start + i] - m);
#pragma unroll
    for (int off = 32; off > 0; off >>= 1) ssum += __shfl_xor(ssum, off);
    float a0 = 0.f, a1 = 0.f, a2 = 0.f, a3 = 0.f;
    int i = 0;
    for (; i + 4 <= deg; i += 4) {
        float w0 = expf(alpha_pos[start + i]     - m);
        float w1 = expf(alpha_pos[start + i + 1] - m);
        float w2 = expf(alpha_pos[start + i + 2] - m);
        float w3 = expf(alpha_pos[start + i + 3] - m);
        int r0 = sdg[start + i].x;
        int r1 = sdg[start + i + 1].x;
        int r2 = sdg[start + i + 2].x;
        int r3 = sdg[start + i + 3].x;
        float4 v0 = *(const float4*)(x + (size_t)r0 * DIM + lane * 4);
        float4 v1 = *(const float4*)(x + (size_t)r1 * DIM + lane * 4);
        float4 v2 = *(const float4*)(x + (size_t)r2 * DIM + lane * 4);
        float4 v3 = *(const float4*)(x + (size_t)r3 * DIM + lane * 4);
        a0 += w0 * v0.x + w1 * v1.x + w2 * v2.x + w3 * v3.x;
        a1 += w0 * v0.y + w1 * v1.y + w2 * v2.y + w3 * v3.y;
        a2 += w0 * v0.z + w1 * v1.z + w2 * v2.z + w3 * v3.z;
        a3 += w0 * v0.w + w1 * v1.w + w2 * v2.w + w3 * v3.w;
    }
    for (; i < deg; ++i) {
        float wgt = expf(alpha_pos[start + i] - m);
        int r = sdg[start + i].x;
        const float4 v = *(const float4*)(x + (size_t)r * DIM + lane * 4);
        a0 += wgt * v.x; a1 += wgt * v.y; a2 += wgt * v.z; a3 += wgt * v.w;
    }
    float inv = 1.f / (ssum + 1e-16f);
    float4 r; r.x = a0 * inv; r.y = a1 * inv; r.z = a2 * inv; r.w = a3 * inv;
    *(float4*)(agg + (size_t)gw * DIM + lane * 4) = r;
}

// ---------------- out = [agg|x] @ [Wa;Wo]^T + biases, MFMA 2-split ---------
__global__ __launch_bounds__(256, 2) void k_out_mfma(
    const float* __restrict__ agg, const float* __restrict__ x,
    const u16* __restrict__ wf2, const float* __restrict__ ba,
    const float* __restrict__ bo, float* __restrict__ outb)
{
    __shared__ u16 p_lds[2][64][256];       // 64 KB; reused as float Cs[64][256]
    const int tid = threadIdx.x;
    const int w = tid >> 6;
    const int lane = tid & 63;
    const int l31 = lane & 31;
    const int g2 = lane >> 5;
    const int n0 = blockIdx.x * 64;
    const unsigned swz = ((unsigned)(l31 & 7)) << 4;

    f32x16 accM[2][2], accC[2][2];
#pragma unroll
    for (int mt = 0; mt < 2; ++mt)
#pragma unroll
        for (int nt = 0; nt < 2; ++nt) { accM[mt][nt] = (f32x16)0.f; accC[mt][nt] = (f32x16)0.f; }

    f16x8 afA[2][2], afB[2][2];

#define PREFA2(DST, GKS) { \
    const u16* pb_ = wf2 + ((size_t)((GKS) * 4 + w) * 4) * 512 + lane * 8; \
    _Pragma("unroll") for (int mt_ = 0; mt_ < 2; ++mt_) \
    _Pragma("unroll") for (int pl_ = 0; pl_ < 2; ++pl_) \
        DST[mt_][pl_] = *(const f16x8*)(const void*)(pb_ + (mt_ * 2 + pl_) * 512); }

#define OSTAGE(SRC) { \
    _Pragma("unroll") for (int i_ = 0; i_ < 16; ++i_) { \
        const int ln_ = w * 16 + i_; \
        float4 v_ = *(const float4*)((SRC) + (size_t)(n0 + ln_) * DIM + lane * 4); \
        float pv_[4] = {v_.x, v_.y, v_.z, v_.w}; \
        u16x4 v1_, v2_; \
        _Pragma("unroll") for (int j_ = 0; j_ < 4; ++j_) { \
            float f_ = pv_[j_]; \
            _Float16 h1_ = (_Float16)f_; \
            _Float16 h2_ = (_Float16)((f_ - (float)h1_) * 2048.f); \
            v1_[j_] = h_bits(h1_); v2_[j_] = h_bits(h2_); } \
        const unsigned off_ = ((unsigned)(lane * 8)) ^ (((unsigned)(ln_ & 7)) << 4); \
        *(u16x4*)((char*)&p_lds[0][ln_][0] + off_) = v1_; \
        *(u16x4*)((char*)&p_lds[1][ln_][0] + off_) = v2_; } }

#define OKSTEP(GKS) { \
    if ((GKS) + 1 < 32) { \
        if ((GKS) & 1) { PREFA2(afA, (GKS) + 1) } else { PREFA2(afB, (GKS) + 1) } \
    } \
    f16x8 bfr[2][2]; \
    _Pragma("unroll") for (int nt_ = 0; nt_ < 2; ++nt_) { \
        const int en_ = nt_ * 32 + l31; \
        const unsigned off_ = ((unsigned)(((GKS) & 15) * 32 + g2 * 16)) ^ swz; \
        _Pragma("unroll") for (int pl_ = 0; pl_ < 2; ++pl_) \
            bfr[nt_][pl_] = *(const f16x8*)(const void*)((const char*)&p_lds[pl_][en_][0] + off_); \
    } \
    _Pragma("unroll") for (int mt_ = 0; mt_ < 2; ++mt_) \
    _Pragma("unroll") for (int nt_ = 0; nt_ < 2; ++nt_) { \
        f16x8 a1_ = ((GKS) & 1) ? afB[mt_][0] : afA[mt_][0]; \
        f16x8 a2_ = ((GKS) & 1) ? afB[mt_][1] : afA[mt_][1]; \
        accM[mt_][nt_] = __builtin_amdgcn_mfma_f32_32x32x16_f16(a1_, bfr[nt_][0], accM[mt_][nt_], 0, 0, 0); \
        accC[mt_][nt_] = __builtin_amdgcn_mfma_f32_32x32x16_f16(a1_, bfr[nt_][1], accC[mt_][nt_], 0, 0, 0); \
        accC[mt_][nt_] = __builtin_amdgcn_mfma_f32_32x32x16_f16(a2_, bfr[nt_][0], accC[mt_][nt_], 0, 0, 0); } }

    PREFA2(afA, 0)
    OSTAGE(agg)
    __syncthreads();
    OKSTEP(0)  OKSTEP(1)  OKSTEP(2)  OKSTEP(3)
    OKSTEP(4)  OKSTEP(5)  OKSTEP(6)  OKSTEP(7)
    OKSTEP(8)  OKSTEP(9)  OKSTEP(10) OKSTEP(11)
    OKSTEP(12) OKSTEP(13) OKSTEP(14) OKSTEP(15)
    __syncthreads();
    OSTAGE(x)
    __syncthreads();
    OKSTEP(16) OKSTEP(17) OKSTEP(18) OKSTEP(19)
    OKSTEP(20) OKSTEP(21) OKSTEP(22) OKSTEP(23)
    OKSTEP(24) OKSTEP(25) OKSTEP(26) OKSTEP(27)
    OKSTEP(28) OKSTEP(29) OKSTEP(30) OKSTEP(31)
#undef OSTAGE
#undef OKSTEP
#undef PREFA2

    // ---- epilogue: bias add + LDS transpose + coalesced store ----
    __syncthreads();
    float* Cs = (float*)(void*)p_lds;       // logical [64 nodes][256 outs], swizzled
#pragma unroll
    for (int mt = 0; mt < 2; ++mt)
#pragma unroll
        for (int r = 0; r < 16; ++r) {
            int o = 64 * w + 32 * mt + (r & 3) + 8 * (r >> 2) + 4 * g2;
            float bs = ba[o] + bo[o];
#pragma unroll
            for (int nt = 0; nt < 2; ++nt) {
                int col = nt * 32 + l31;
                float hv = accM[mt][nt][r] + accC[mt][nt][r] * 4.8828125e-4f + bs;
                unsigned ob = ((unsigned)(col * 1024 + o * 4)) ^ (((unsigned)(col & 31)) << 4);
                *(float*)((char*)Cs + ob) = hv;
            }
        }
    __syncthreads();
#pragma unroll
    for (int i = 0; i < 16; ++i) {
        int ln = w * 16 + i;
        unsigned rb = ((unsigned)(ln * 1024 + lane * 16)) ^ (((unsigned)(ln & 31)) << 4);
        float4 val = *(const float4*)((const char*)Cs + rb);
        *(float4*)(outb + (size_t)(n0 + ln) * DIM + lane * 4) = val;
    }
}

// ---------------- BN column stats (fp64 partials) ----------------
__global__ void k_colstat(const float* __restrict__ outb, double* __restrict__ psum,
                          double* __restrict__ psq) {
    int g = blockIdx.x, t = threadIdx.x;
    double s = 0.0, q = 0.0;
    const float* p = outb + (size_t)g * 256 * DIM + t;
    for (int r = 0; r < 256; ++r) { double v = (double)p[(size_t)r * DIM]; s += v; q += v * v; }
    psum[g * DIM + t] = s;
    psq[g * DIM + t] = q;
}

__global__ void k_bnparam(const double* __restrict__ psum, const double* __restrict__ psq,
                          const float* __restrict__ gamma, const float* __restrict__ beta,
                          float* __restrict__ scale, float* __restrict__ shift) {
    int t = threadIdx.x;
    double s = 0.0, q = 0.0;
    for (int g = 0; g < 32; ++g) { s += psum[g * DIM + t]; q += psq[g * DIM + t]; }
    double mean = s / (double)NODES;
    double var = q / (double)NODES - mean * mean;
    float sc = (float)((double)gamma[t] / sqrt(var + 1e-5));
    scale[t] = sc;
    shift[t] = (float)((double)beta[t] - mean * (double)sc);
}

// ---------------- affine + SELU + pooling score ----------------
__global__ void k_bnselu(float* __restrict__ outb, const float* __restrict__ scale,
                         const float* __restrict__ shift, const float* __restrict__ yw,
                         const float* __restrict__ yb, float* __restrict__ y) {
    int gw = (blockIdx.x * blockDim.x + threadIdx.x) >> 6;
    int lane = threadIdx.x & 63;
    if (gw >= NODES) return;
    float4 v  = *(const float4*)(outb + (size_t)gw * DIM + lane * 4);
    float4 sc = *(const float4*)(scale + lane * 4);
    float4 sh = *(const float4*)(shift + lane * 4);
    const float SL = 1.0507009873554805f, SA = 1.6732632423543772f;
    float4 o;
    o.x = v.x * sc.x + sh.x;
    o.y = v.y * sc.y + sh.y;
    o.z = v.z * sc.z + sh.z;
    o.w = v.w * sc.w + sh.w;
    o.x = (o.x > 0.f) ? SL * o.x : SL * SA * expm1f(o.x);
    o.y = (o.y > 0.f) ? SL * o.y : SL * SA * expm1f(o.y);
    o.z = (o.z > 0.f) ? SL * o.z : SL * SA * expm1f(o.z);
    o.w = (o.w > 0.f) ? SL * o.w : SL * SA * expm1f(o.w);
    *(float4*)(outb + (size_t)gw * DIM + lane * 4) = o;
    float4 w = *(const float4*)(yw + lane * 4);
    float z = o.x * w.x + o.y * w.y + o.z * w.z + o.w * w.w;
#pragma unroll
    for (int off = 32; off > 0; off >>= 1) z += __shfl_xor(z, off);
    if (lane == 0) y[gw] = 1.f / (1.f + expf(-(z + yb[0])));
}

// ---------------- per-batch bitonic top-k (val desc, idx asc) ----------------
__global__ void k_topk(const float* __restrict__ y, float* __restrict__ svals,
                       int* __restrict__ sidx) {
    __shared__ float v[1024];
    __shared__ int  id[1024];
    int b = blockIdx.x, t = threadIdx.x;   // 512 threads
    v[t] = y[b * 1024 + t];           id[t] = t;
    v[t + 512] = y[b * 1024 + t + 512]; id[t + 512] = t + 512;
    __syncthreads();
    for (int k = 2; k <= 1024; k <<= 1) {
        for (int j = k >> 1; j > 0; j >>= 1) {
            for (int i = t; i < 1024; i += 512) {
                int l = i ^ j;
                if (l > i) {
                    float vi = v[i], vl = v[l];
                    int ii = id[i], il = id[l];
                    bool precede = (vi > vl) || (vi == vl && ii < il);
                    bool dirDesc = ((i & k) == 0);
                    bool sw = dirDesc ? !precede : precede;
                    if (sw) { v[i] = vl; v[l] = vi; id[i] = il; id[l] = ii; }
                }
            }
            __syncthreads();
        }
    }
    if (t < 512) { svals[b * 512 + t] = v[t]; sidx[b * 512 + t] = id[t]; }
}

// ---------------- gather + gate ----------------
__global__ void k_gather(const float* __restrict__ outb, const float* __restrict__ svals,
                         const int* __restrict__ sidx, float* __restrict__ dout) {
    int gw = (blockIdx.x * blockDim.x + threadIdx.x) >> 6;
    int lane = threadIdx.x & 63;
    int b = gw >> 9, r = gw & 511;
    float val = svals[b * 512 + r];
    int idn = sidx[b * 512 + r];
    float4 vv = *(const float4*)(outb + (size_t)(b * 1024 + idn) * DIM + lane * 4);
    vv.x *= val; vv.y *= val; vv.z *= val; vv.w *= val;
    *(float4*)(dout + (size_t)(b * 512 + r) * DIM + lane * 4) = vv;
}

extern "C" void kernel_launch(void* const* d_in, const int* in_sizes, int n_in,
                              void* d_out, int out_size, void* d_ws, size_t ws_size,
                              hipStream_t stream) {
    const float* x     = (const float*)d_in[0];
    const int* edges   = (const int*)d_in[1];
    const float* att_w = (const float*)d_in[2];
    const float* att_b = (const float*)d_in[3];
    const float* amap  = (const float*)d_in[4];
    const float* pwa_w = (const float*)d_in[5];
    const float* pwa_b = (const float*)d_in[6];
    const float* pwo_w = (const float*)d_in[7];
    const float* pwo_b = (const float*)d_in[8];
    const float* gamma = (const float*)d_in[9];
    const float* beta  = (const float*)d_in[10];
    const float* yw    = (const float*)d_in[11];
    const float* yb    = (const float*)d_in[12];
    float* out = (float*)d_out;
    const int* src = edges;
    const int* dst = edges + NEDGE;

    char* ws = (char*)d_ws;
    size_t off = 0;
    auto alloc = [&](size_t b) { void* p = ws + off; off = (off + b + 255) & ~(size_t)255; return p; };
    float* alpha  = (float*)alloc((size_t)NEDGE * 4);      // CSR-position order
    float* apart  = (float*)alloc((size_t)4 * NEDGE * 4);  // per-consumer-wave partials
    int2*  sdg    = (int2*)alloc((size_t)NEDGE * 8);       // (src,dst) per CSR position
    float* agg    = (float*)alloc((size_t)NODES * DIM * 4);
    float* outb   = (float*)alloc((size_t)NODES * DIM * 4);
    int*   deg    = (int*)alloc(NODES * 4);
    int*   rowptr = (int*)alloc((NODES + 1) * 4);
    int*   cursor = (int*)alloc(NODES * 4);
    double* psum  = (double*)alloc(32 * DIM * 8);
    double* psq   = (double*)alloc(32 * DIM * 8);
    float* scale  = (float*)alloc(DIM * 4);
    float* shift  = (float*)alloc(DIM * 4);
    float* yv     = (float*)alloc(NODES * 4);
    float* svals  = (float*)alloc(8 * 512 * 4);
    int*   sidx   = (int*)alloc(8 * 512 * 4);
    u16*   wf     = (u16*)alloc((size_t)16 * 4 * 4 * 512 * 2);
    u16*   wf2    = (u16*)alloc((size_t)32 * 4 * 4 * 512 * 2);

    hipMemsetAsync(deg, 0, NODES * 4, stream);
    k_wfrag<<<32, 256, 0, stream>>>(att_w, wf);
    k_wfrag2<<<64, 256, 0, stream>>>(pwa_w, pwo_w, wf2);
    k_deg<<<NEDGE / 256, 256, 0, stream>>>(dst, deg);
    k_scan<<<1, 256, 0, stream>>>(deg, rowptr, cursor);
    k_fill<<<NEDGE / 256, 256, 0, stream>>>(src, dst, cursor, sdg);
    k_alpha_v13<<<NEDGE / 256, 512, 0, stream>>>(x, sdg, wf, att_b, amap, apart);
    k_asum<<<NEDGE / 256, 256, 0, stream>>>(apart, alpha);
    k_aggregate<<<NODES / 4, 256, 0, stream>>>(x, alpha, rowptr, sdg, agg);
    k_out_mfma<<<NODES / 64, 256, 0, stream>>>(agg, x, wf2, pwa_b, pwo_b, outb);
    k_colstat<<<32, 256, 0, stream>>>(outb, psum, psq);
    k_bnparam<<<1, 256, 0, stream>>>(psum, psq, gamma, beta, scale, shift);
    k_bnselu<<<NODES / 4, 256, 0, stream>>>(outb, scale, shift, yw, yb, yv);
    k_topk<<<8, 512, 0, stream>>>(yv, svals, sidx);
    k_gather<<<(8 * 512) / 4, 256, 0, stream>>>(outb, svals, sidx, out);
}

// Round 14
// 289.945 us; speedup vs baseline: 1.0167x; 1.0167x over previous
//
#include <hip/hip_runtime.h>
#include <math.h>

#define NODES 8192
#define NEDGE 262144
#define DIM 256

typedef float f32x16 __attribute__((ext_vector_type(16)));
typedef _Float16 f16x8 __attribute__((ext_vector_type(8)));
typedef unsigned short u16;
typedef u16 u16x8 __attribute__((ext_vector_type(8)));
typedef u16 u16x4 __attribute__((ext_vector_type(4)));

__device__ __forceinline__ float fast_tanh(float x) {
    float t = __expf(2.f * x);
    return 1.f - 2.f * __builtin_amdgcn_rcpf(t + 1.f);
}

__device__ __forceinline__ u16 h_bits(_Float16 h) {
    u16 r; __builtin_memcpy(&r, &h, 2); return r;
}

// ---------------- CSR build (dst-indexed) ----------------
__global__ void k_deg(const int* __restrict__ dst, int* __restrict__ deg) {
    int e = blockIdx.x * blockDim.x + threadIdx.x;
    if (e < NEDGE) atomicAdd(&deg[dst[e]], 1);
}

__global__ void k_scan(const int* __restrict__ deg, int* __restrict__ rowptr,
                       int* __restrict__ cursor) {
    __shared__ int part[256];
    int t = threadIdx.x;
    int base = t * 32;
    int local[32];
    int s = 0;
    for (int i = 0; i < 32; ++i) { local[i] = s; s += deg[base + i]; }
    part[t] = s;
    __syncthreads();
    for (int off = 1; off < 256; off <<= 1) {
        int v = (t >= off) ? part[t - off] : 0;
        __syncthreads();
        part[t] += v;
        __syncthreads();
    }
    int excl = (t == 0) ? 0 : part[t - 1];
    for (int i = 0; i < 32; ++i) {
        int v = excl + local[i];
        rowptr[base + i] = v;
        cursor[base + i] = v;
    }
    if (t == 255) rowptr[NODES] = part[255];
}

__global__ void k_fill(const int* __restrict__ src, const int* __restrict__ dst,
                       int* __restrict__ cursor, int2* __restrict__ sdg) {
    int e = blockIdx.x * blockDim.x + threadIdx.x;
    if (e < NEDGE) {
        int pos = atomicAdd(&cursor[dst[e]], 1);
        sdg[pos] = make_int2(src[e], dst[e]);
    }
}

// ---------------- att_w -> fp16 2-plane fragment order ----------------
__global__ void k_wfrag(const float* __restrict__ W, u16* __restrict__ wf) {
    int t = blockIdx.x * blockDim.x + threadIdx.x;
    if (t >= 16 * 4 * 2 * 64) return;
    int lane = t & 63;
    int mt = (t >> 6) & 1;
    int w = (t >> 7) & 3;
    int gks = t >> 9;
    int row = w * 64 + mt * 32 + (lane & 31);
    int k0 = gks * 16 + (lane >> 5) * 8;
    const float* p = W + (size_t)row * DIM + k0;
    u16x8 v1, v2;
#pragma unroll
    for (int j = 0; j < 8; ++j) {
        float f = p[j];
        _Float16 h1 = (_Float16)f;
        _Float16 h2 = (_Float16)((f - (float)h1) * 2048.f);
        v1[j] = h_bits(h1);
        v2[j] = h_bits(h2);
    }
    size_t base = ((size_t)(gks * 4 + w) * 4 + mt * 2) * 512 + lane * 8;
    *(u16x8*)(wf + base)       = v1;
    *(u16x8*)(wf + base + 512) = v2;
}

// ---------------- [pwa_w ; pwo_w] -> fragment order, K=512 (gks 0..31) -----
__global__ void k_wfrag2(const float* __restrict__ Wa, const float* __restrict__ Wo,
                         u16* __restrict__ wf2) {
    int t = blockIdx.x * blockDim.x + threadIdx.x;
    if (t >= 32 * 4 * 2 * 64) return;
    int lane = t & 63;
    int mt = (t >> 6) & 1;
    int w = (t >> 7) & 3;
    int gks = t >> 9;                       // 0..31
    const float* W = (gks < 16) ? Wa : Wo;
    int row = w * 64 + mt * 32 + (lane & 31);
    int k0 = (gks & 15) * 16 + (lane >> 5) * 8;
    const float* p = W + (size_t)row * DIM + k0;
    u16x8 v1, v2;
#pragma unroll
    for (int j = 0; j < 8; ++j) {
        float f = p[j];
        _Float16 h1 = (_Float16)f;
        _Float16 h2 = (_Float16)((f - (float)h1) * 2048.f);
        v1[j] = h_bits(h1);
        v2[j] = h_bits(h2);
    }
    size_t base = ((size_t)(gks * 4 + w) * 4 + mt * 2) * 512 + lane * 8;
    *(u16x8*)(wf2 + base)       = v1;
    *(u16x8*)(wf2 + base + 512) = v2;
}

// ---------------- alpha, v14: 64x32 wave tile -> 3 waves/SIMD ----------------
// Block: 256 thr / 4 waves, 32 edges, 256 outs. Wave w: 64 outs (mt=2) x
// 32 edges (nt=1). acc = 64 f32 -> ~170 regs -> 3 waves/SIMD.
// LDS 32 KB single-stage; depth-2 A prefetch (3-buffer rotation).
__global__ __launch_bounds__(256, 3) void k_alpha_v14(
    const float* __restrict__ x, const int2* __restrict__ sdg,
    const u16* __restrict__ wf, const float* __restrict__ bias,
    const float* __restrict__ amap, float* __restrict__ alpha_pos)
{
    __shared__ u16 p_lds[2][32][256];   // 32 KB; [plane][edge][k], byte ^ ((edge&7)<<4)
    const int tid = threadIdx.x;
    const int w = tid >> 6;
    const int lane = tid & 63;
    const int l31 = lane & 31;
    const int g2 = lane >> 5;
    const int bid = blockIdx.x;
    const int wg = (bid & 7) * 1024 + (bid >> 3);   // XCD swizzle (8192%8==0)
    const int e0 = wg * 32;
    const int ebase = e0 + w * 8;
    const unsigned swz = ((unsigned)(l31 & 7)) << 4;

    f32x16 accM[2], accC[2];
#pragma unroll
    for (int mt = 0; mt < 2; ++mt) { accM[mt] = (f32x16)0.f; accC[mt] = (f32x16)0.f; }

    f16x8 afA[2][2], afB[2][2], afC[2][2];

#define PREFA(DST, GKS) { \
    const u16* pb_ = wf + ((size_t)((GKS) * 4 + w) * 4) * 512 + lane * 8; \
    _Pragma("unroll") for (int mt_ = 0; mt_ < 2; ++mt_) \
    _Pragma("unroll") for (int pl_ = 0; pl_ < 2; ++pl_) \
        DST[mt_][pl_] = *(const f16x8*)(const void*)(pb_ + (mt_ * 2 + pl_) * 512); }

#define KS(GKS, USE, PF) { \
    if ((GKS) + 2 < 16) { PREFA(PF, (GKS) + 2) } \
    f16x8 bfr[2]; \
    { \
        const unsigned off_ = ((unsigned)((GKS) * 32 + g2 * 16)) ^ swz; \
        _Pragma("unroll") for (int pl_ = 0; pl_ < 2; ++pl_) \
            bfr[pl_] = *(const f16x8*)(const void*)((const char*)&p_lds[pl_][l31][0] + off_); \
    } \
    _Pragma("unroll") for (int mt_ = 0; mt_ < 2; ++mt_) { \
        accM[mt_] = __builtin_amdgcn_mfma_f32_32x32x16_f16(USE[mt_][0], bfr[0], accM[mt_], 0, 0, 0); \
        accC[mt_] = __builtin_amdgcn_mfma_f32_32x32x16_f16(USE[mt_][0], bfr[1], accC[mt_], 0, 0, 0); \
        accC[mt_] = __builtin_amdgcn_mfma_f32_32x32x16_f16(USE[mt_][1], bfr[0], accC[mt_], 0, 0, 0); } }

    // preload A(0), A(1) before the gather burst
    PREFA(afA, 0)
    PREFA(afB, 1)

    // ---- cooperative staging: wave w stages edges [8w, 8w+8), full K ----
#pragma unroll
    for (int i = 0; i < 8; ++i) {
        int2 sd = sdg[ebase + i];
        float4 a = *(const float4*)(x + (size_t)sd.x * DIM + lane * 4);
        float4 b = *(const float4*)(x + (size_t)sd.y * DIM + lane * 4);
        float pv[4] = {a.x * b.x, a.y * b.y, a.z * b.z, a.w * b.w};
        u16x4 v1, v2;
#pragma unroll
        for (int j = 0; j < 4; ++j) {
            float f = pv[j];
            _Float16 h1 = (_Float16)f;
            _Float16 h2 = (_Float16)((f - (float)h1) * 2048.f);
            v1[j] = h_bits(h1);
            v2[j] = h_bits(h2);
        }
        const int le = w * 8 + i;
        const unsigned off = ((unsigned)(lane * 8)) ^ (((unsigned)(le & 7)) << 4);
        *(u16x4*)((char*)&p_lds[0][le][0] + off) = v1;
        *(u16x4*)((char*)&p_lds[1][le][0] + off) = v2;
    }
    __syncthreads();

    // ---- 16-step MFMA burst, A prefetched 2 steps ahead ----
    KS(0,  afA, afC) KS(1,  afB, afA) KS(2,  afC, afB)
    KS(3,  afA, afC) KS(4,  afB, afA) KS(5,  afC, afB)
    KS(6,  afA, afC) KS(7,  afB, afA) KS(8,  afC, afB)
    KS(9,  afA, afC) KS(10, afB, afA) KS(11, afC, afB)
    KS(12, afA, afC) KS(13, afB, afA) KS(14, afC, afB)
    KS(15, afA, afC)
#undef KS
#undef PREFA

    // ---- epilogue: alpha = sum_out amap*tanh(h+bias), h = M + C*2^-11 ----
    float part = 0.f;
#pragma unroll
    for (int mt = 0; mt < 2; ++mt)
#pragma unroll
        for (int r = 0; r < 16; ++r) {
            int o = 64 * w + 32 * mt + (r & 3) + 8 * (r >> 2) + 4 * g2;
            float bo = bias[o], ao = amap[o];
            float h = accM[mt][r] + accC[mt][r] * 4.8828125e-4f;
            part += ao * fast_tanh(h + bo);
        }
    part += __shfl_xor(part, 32);
    __syncthreads();                       // all LDS reads done; reuse for reduction
    float* red = (float*)(void*)p_lds;     // [4][32]
    if (lane < 32) red[w * 32 + lane] = part;
    __syncthreads();
    if (tid < 32) alpha_pos[e0 + tid] = red[tid] + red[32 + tid] + red[64 + tid] + red[96 + tid];
}

// ---------------- segment softmax + weighted aggregate (unroll-4) ----------
__global__ void k_aggregate(
    const float* __restrict__ x, const float* __restrict__ alpha_pos,
    const int* __restrict__ rowptr, const int2* __restrict__ sdg,
    float* __restrict__ agg)
{
    int gw = (blockIdx.x * blockDim.x + threadIdx.x) >> 6;
    int lane = threadIdx.x & 63;
    if (gw >= NODES) return;
    int start = rowptr[gw], end = rowptr[gw + 1];
    int deg = end - start;
    float m = -INFINITY;
    for (int i = lane; i < deg; i += 64) m = fmaxf(m, alpha_pos[start + i]);
#pragma unroll
    for (int off = 32; off > 0; off >>= 1) m = fmaxf(m, __shfl_xor(m, off));
    float ssum = 0.f;
    for (int i = lane; i < deg; i += 64) ssum += expf(alpha_pos[start + i] - m);
#pragma unroll
    for (int off = 32; off > 0; off >>= 1) ssum += __shfl_xor(ssum, off);
    float a0 = 0.f, a1 = 0.f, a2 = 0.f, a3 = 0.f;
    int i = 0;
    for (; i + 4 <= deg; i += 4) {
        float w0 = expf(alpha_pos[start + i]     - m);
        float w1 = expf(alpha_pos[start + i + 1] - m);
        float w2 = expf(alpha_pos[start + i + 2] - m);
        float w3 = expf(alpha_pos[start + i + 3] - m);
        int r0 = sdg[start + i].x;
        int r1 = sdg[start + i + 1].x;
        int r2 = sdg[start + i + 2].x;
        int r3 = sdg[start + i + 3].x;
        float4 v0 = *(const float4*)(x + (size_t)r0 * DIM + lane * 4);
        float4 v1 = *(const float4*)(x + (size_t)r1 * DIM + lane * 4);
        float4 v2 = *(const float4*)(x + (size_t)r2 * DIM + lane * 4);
        float4 v3 = *(const float4*)(x + (size_t)r3 * DIM + lane * 4);
        a0 += w0 * v0.x + w1 * v1.x + w2 * v2.x + w3 * v3.x;
        a1 += w0 * v0.y + w1 * v1.y + w2 * v2.y + w3 * v3.y;
        a2 += w0 * v0.z + w1 * v1.z + w2 * v2.z + w3 * v3.z;
        a3 += w0 * v0.w + w1 * v1.w + w2 * v2.w + w3 * v3.w;
    }
    for (; i < deg; ++i) {
        float wgt = expf(alpha_pos[start + i] - m);
        int r = sdg[start + i].x;
        const float4 v = *(const float4*)(x + (size_t)r * DIM + lane * 4);
        a0 += wgt * v.x; a1 += wgt * v.y; a2 += wgt * v.z; a3 += wgt * v.w;
    }
    float inv = 1.f / (ssum + 1e-16f);
    float4 r; r.x = a0 * inv; r.y = a1 * inv; r.z = a2 * inv; r.w = a3 * inv;
    *(float4*)(agg + (size_t)gw * DIM + lane * 4) = r;
}

// ---------------- out = [agg|x] @ [Wa;Wo]^T + biases, MFMA 2-split ---------
__global__ __launch_bounds__(256, 2) void k_out_mfma(
    const float* __restrict__ agg, const float* __restrict__ x,
    const u16* __restrict__ wf2, const float* __restrict__ ba,
    const float* __restrict__ bo, float* __restrict__ outb)
{
    __shared__ u16 p_lds[2][64][256];       // 64 KB; reused as float Cs[64][256]
    const int tid = threadIdx.x;
    const int w = tid >> 6;
    const int lane = tid & 63;
    const int l31 = lane & 31;
    const int g2 = lane >> 5;
    const int n0 = blockIdx.x * 64;
    const unsigned swz = ((unsigned)(l31 & 7)) << 4;

    f32x16 accM[2][2], accC[2][2];
#pragma unroll
    for (int mt = 0; mt < 2; ++mt)
#pragma unroll
        for (int nt = 0; nt < 2; ++nt) { accM[mt][nt] = (f32x16)0.f; accC[mt][nt] = (f32x16)0.f; }

    f16x8 afA[2][2], afB[2][2];

#define PREFA2(DST, GKS) { \
    const u16* pb_ = wf2 + ((size_t)((GKS) * 4 + w) * 4) * 512 + lane * 8; \
    _Pragma("unroll") for (int mt_ = 0; mt_ < 2; ++mt_) \
    _Pragma("unroll") for (int pl_ = 0; pl_ < 2; ++pl_) \
        DST[mt_][pl_] = *(const f16x8*)(const void*)(pb_ + (mt_ * 2 + pl_) * 512); }

#define OSTAGE(SRC) { \
    _Pragma("unroll") for (int i_ = 0; i_ < 16; ++i_) { \
        const int ln_ = w * 16 + i_; \
        float4 v_ = *(const float4*)((SRC) + (size_t)(n0 + ln_) * DIM + lane * 4); \
        float pv_[4] = {v_.x, v_.y, v_.z, v_.w}; \
        u16x4 v1_, v2_; \
        _Pragma("unroll") for (int j_ = 0; j_ < 4; ++j_) { \
            float f_ = pv_[j_]; \
            _Float16 h1_ = (_Float16)f_; \
            _Float16 h2_ = (_Float16)((f_ - (float)h1_) * 2048.f); \
            v1_[j_] = h_bits(h1_); v2_[j_] = h_bits(h2_); } \
        const unsigned off_ = ((unsigned)(lane * 8)) ^ (((unsigned)(ln_ & 7)) << 4); \
        *(u16x4*)((char*)&p_lds[0][ln_][0] + off_) = v1_; \
        *(u16x4*)((char*)&p_lds[1][ln_][0] + off_) = v2_; } }

#define OKSTEP(GKS) { \
    if ((GKS) + 1 < 32) { \
        if ((GKS) & 1) { PREFA2(afA, (GKS) + 1) } else { PREFA2(afB, (GKS) + 1) } \
    } \
    f16x8 bfr[2][2]; \
    _Pragma("unroll") for (int nt_ = 0; nt_ < 2; ++nt_) { \
        const int en_ = nt_ * 32 + l31; \
        const unsigned off_ = ((unsigned)(((GKS) & 15) * 32 + g2 * 16)) ^ swz; \
        _Pragma("unroll") for (int pl_ = 0; pl_ < 2; ++pl_) \
            bfr[nt_][pl_] = *(const f16x8*)(const void*)((const char*)&p_lds[pl_][en_][0] + off_); \
    } \
    _Pragma("unroll") for (int mt_ = 0; mt_ < 2; ++mt_) \
    _Pragma("unroll") for (int nt_ = 0; nt_ < 2; ++nt_) { \
        f16x8 a1_ = ((GKS) & 1) ? afB[mt_][0] : afA[mt_][0]; \
        f16x8 a2_ = ((GKS) & 1) ? afB[mt_][1] : afA[mt_][1]; \
        accM[mt_][nt_] = __builtin_amdgcn_mfma_f32_32x32x16_f16(a1_, bfr[nt_][0], accM[mt_][nt_], 0, 0, 0); \
        accC[mt_][nt_] = __builtin_amdgcn_mfma_f32_32x32x16_f16(a1_, bfr[nt_][1], accC[mt_][nt_], 0, 0, 0); \
        accC[mt_][nt_] = __builtin_amdgcn_mfma_f32_32x32x16_f16(a2_, bfr[nt_][0], accC[mt_][nt_], 0, 0, 0); } }

    PREFA2(afA, 0)
    OSTAGE(agg)
    __syncthreads();
    OKSTEP(0)  OKSTEP(1)  OKSTEP(2)  OKSTEP(3)
    OKSTEP(4)  OKSTEP(5)  OKSTEP(6)  OKSTEP(7)
    OKSTEP(8)  OKSTEP(9)  OKSTEP(10) OKSTEP(11)
    OKSTEP(12) OKSTEP(13) OKSTEP(14) OKSTEP(15)
    __syncthreads();
    OSTAGE(x)
    __syncthreads();
    OKSTEP(16) OKSTEP(17) OKSTEP(18) OKSTEP(19)
    OKSTEP(20) OKSTEP(21) OKSTEP(22) OKSTEP(23)
    OKSTEP(24) OKSTEP(25) OKSTEP(26) OKSTEP(27)
    OKSTEP(28) OKSTEP(29) OKSTEP(30) OKSTEP(31)
#undef OSTAGE
#undef OKSTEP
#undef PREFA2

    // ---- epilogue: bias add + LDS transpose + coalesced store ----
    __syncthreads();
    float* Cs = (float*)(void*)p_lds;       // logical [64 nodes][256 outs], swizzled
#pragma unroll
    for (int mt = 0; mt < 2; ++mt)
#pragma unroll
        for (int r = 0; r < 16; ++r) {
            int o = 64 * w + 32 * mt + (r & 3) + 8 * (r >> 2) + 4 * g2;
            float bs = ba[o] + bo[o];
#pragma unroll
            for (int nt = 0; nt < 2; ++nt) {
                int col = nt * 32 + l31;
                float hv = accM[mt][nt][r] + accC[mt][nt][r] * 4.8828125e-4f + bs;
                unsigned ob = ((unsigned)(col * 1024 + o * 4)) ^ (((unsigned)(col & 31)) << 4);
                *(float*)((char*)Cs + ob) = hv;
            }
        }
    __syncthreads();
#pragma unroll
    for (int i = 0; i < 16; ++i) {
        int ln = w * 16 + i;
        unsigned rb = ((unsigned)(ln * 1024 + lane * 16)) ^ (((unsigned)(ln & 31)) << 4);
        float4 val = *(const float4*)((const char*)Cs + rb);
        *(float4*)(outb + (size_t)(n0 + ln) * DIM + lane * 4) = val;
    }
}

// ---------------- BN column stats (fp64 partials) ----------------
__global__ void k_colstat(const float* __restrict__ outb, double* __restrict__ psum,
                          double* __restrict__ psq) {
    int g = blockIdx.x, t = threadIdx.x;
    double s = 0.0, q = 0.0;
    const float* p = outb + (size_t)g * 256 * DIM + t;
    for (int r = 0; r < 256; ++r) { double v = (double)p[(size_t)r * DIM]; s += v; q += v * v; }
    psum[g * DIM + t] = s;
    psq[g * DIM + t] = q;
}

__global__ void k_bnparam(const double* __restrict__ psum, const double* __restrict__ psq,
                          const float* __restrict__ gamma, const float* __restrict__ beta,
                          float* __restrict__ scale, float* __restrict__ shift) {
    int t = threadIdx.x;
    double s = 0.0, q = 0.0;
    for (int g = 0; g < 32; ++g) { s += psum[g * DIM + t]; q += psq[g * DIM + t]; }
    double mean = s / (double)NODES;
    double var = q / (double)NODES - mean * mean;
    float sc = (float)((double)gamma[t] / sqrt(var + 1e-5));
    scale[t] = sc;
    shift[t] = (float)((double)beta[t] - mean * (double)sc);
}

// ---------------- affine + SELU + pooling score ----------------
__global__ void k_bnselu(float* __restrict__ outb, const float* __restrict__ scale,
                         const float* __restrict__ shift, const float* __restrict__ yw,
                         const float* __restrict__ yb, float* __restrict__ y) {
    int gw = (blockIdx.x * blockDim.x + threadIdx.x) >> 6;
    int lane = threadIdx.x & 63;
    if (gw >= NODES) return;
    float4 v  = *(const float4*)(outb + (size_t)gw * DIM + lane * 4);
    float4 sc = *(const float4*)(scale + lane * 4);
    float4 sh = *(const float4*)(shift + lane * 4);
    const float SL = 1.0507009873554805f, SA = 1.6732632423543772f;
    float4 o;
    o.x = v.x * sc.x + sh.x;
    o.y = v.y * sc.y + sh.y;
    o.z = v.z * sc.z + sh.z;
    o.w = v.w * sc.w + sh.w;
    o.x = (o.x > 0.f) ? SL * o.x : SL * SA * expm1f(o.x);
    o.y = (o.y > 0.f) ? SL * o.y : SL * SA * expm1f(o.y);
    o.z = (o.z > 0.f) ? SL * o.z : SL * SA * expm1f(o.z);
    o.w = (o.w > 0.f) ? SL * o.w : SL * SA * expm1f(o.w);
    *(float4*)(outb + (size_t)gw * DIM + lane * 4) = o;
    float4 w = *(const float4*)(yw + lane * 4);
    float z = o.x * w.x + o.y * w.y + o.z * w.z + o.w * w.w;
#pragma unroll
    for (int off = 32; off > 0; off >>= 1) z += __shfl_xor(z, off);
    if (lane == 0) y[gw] = 1.f / (1.f + expf(-(z + yb[0])));
}

// ---------------- per-batch bitonic top-k (val desc, idx asc) ----------------
__global__ void k_topk(const float* __restrict__ y, float* __restrict__ svals,
                       int* __restrict__ sidx) {
    __shared__ float v[1024];
    __shared__ int  id[1024];
    int b = blockIdx.x, t = threadIdx.x;   // 512 threads
    v[t] = y[b * 1024 + t];           id[t] = t;
    v[t + 512] = y[b * 1024 + t + 512]; id[t + 512] = t + 512;
    __syncthreads();
    for (int k = 2; k <= 1024; k <<= 1) {
        for (int j = k >> 1; j > 0; j >>= 1) {
            for (int i = t; i < 1024; i += 512) {
                int l = i ^ j;
                if (l > i) {
                    float vi = v[i], vl = v[l];
                    int ii = id[i], il = id[l];
                    bool precede = (vi > vl) || (vi == vl && ii < il);
                    bool dirDesc = ((i & k) == 0);
                    bool sw = dirDesc ? !precede : precede;
                    if (sw) { v[i] = vl; v[l] = vi; id[i] = il; id[l] = ii; }
                }
            }
            __syncthreads();
        }
    }
    if (t < 512) { svals[b * 512 + t] = v[t]; sidx[b * 512 + t] = id[t]; }
}

// ---------------- gather + gate ----------------
__global__ void k_gather(const float* __restrict__ outb, const float* __restrict__ svals,
                         const int* __restrict__ sidx, float* __restrict__ dout) {
    int gw = (blockIdx.x * blockDim.x + threadIdx.x) >> 6;
    int lane = threadIdx.x & 63;
    int b = gw >> 9, r = gw & 511;
    float val = svals[b * 512 + r];
    int idn = sidx[b * 512 + r];
    float4 vv = *(const float4*)(outb + (size_t)(b * 1024 + idn) * DIM + lane * 4);
    vv.x *= val; vv.y *= val; vv.z *= val; vv.w *= val;
    *(float4*)(dout + (size_t)(b * 512 + r) * DIM + lane * 4) = vv;
}

extern "C" void kernel_launch(void* const* d_in, const int* in_sizes, int n_in,
                              void* d_out, int out_size, void* d_ws, size_t ws_size,
                              hipStream_t stream) {
    const float* x     = (const float*)d_in[0];
    const int* edges   = (const int*)d_in[1];
    const float* att_w = (const float*)d_in[2];
    const float* att_b = (const float*)d_in[3];
    const float* amap  = (const float*)d_in[4];
    const float* pwa_w = (const float*)d_in[5];
    const float* pwa_b = (const float*)d_in[6];
    const float* pwo_w = (const float*)d_in[7];
    const float* pwo_b = (const float*)d_in[8];
    const float* gamma = (const float*)d_in[9];
    const float* beta  = (const float*)d_in[10];
    const float* yw    = (const float*)d_in[11];
    const float* yb    = (const float*)d_in[12];
    float* out = (float*)d_out;
    const int* src = edges;
    const int* dst = edges + NEDGE;

    char* ws = (char*)d_ws;
    size_t off = 0;
    auto alloc = [&](size_t b) { void* p = ws + off; off = (off + b + 255) & ~(size_t)255; return p; };
    float* alpha  = (float*)alloc((size_t)NEDGE * 4);      // CSR-position order
    int2*  sdg    = (int2*)alloc((size_t)NEDGE * 8);       // (src,dst) per CSR position
    float* agg    = (float*)alloc((size_t)NODES * DIM * 4);
    float* outb   = (float*)alloc((size_t)NODES * DIM * 4);
    int*   deg    = (int*)alloc(NODES * 4);
    int*   rowptr = (int*)alloc((NODES + 1) * 4);
    int*   cursor = (int*)alloc(NODES * 4);
    double* psum  = (double*)alloc(32 * DIM * 8);
    double* psq   = (double*)alloc(32 * DIM * 8);
    float* scale  = (float*)alloc(DIM * 4);
    float* shift  = (float*)alloc(DIM * 4);
    float* yv     = (float*)alloc(NODES * 4);
    float* svals  = (float*)alloc(8 * 512 * 4);
    int*   sidx   = (int*)alloc(8 * 512 * 4);
    u16*   wf     = (u16*)alloc((size_t)16 * 4 * 4 * 512 * 2);
    u16*   wf2    = (u16*)alloc((size_t)32 * 4 * 4 * 512 * 2);

    hipMemsetAsync(deg, 0, NODES * 4, stream);
    k_wfrag<<<32, 256, 0, stream>>>(att_w, wf);
    k_wfrag2<<<64, 256, 0, stream>>>(pwa_w, pwo_w, wf2);
    k_deg<<<NEDGE / 256, 256, 0, stream>>>(dst, deg);
    k_scan<<<1, 256, 0, stream>>>(deg, rowptr, cursor);
    k_fill<<<NEDGE / 256, 256, 0, stream>>>(src, dst, cursor, sdg);
    k_alpha_v14<<<NEDGE / 32, 256, 0, stream>>>(x, sdg, wf, att_b, amap, alpha);
    k_aggregate<<<NODES / 4, 256, 0, stream>>>(x, alpha, rowptr, sdg, agg);
    k_out_mfma<<<NODES / 64, 256, 0, stream>>>(agg, x, wf2, pwa_b, pwo_b, outb);
    k_colstat<<<32, 256, 0, stream>>>(outb, psum, psq);
    k_bnparam<<<1, 256, 0, stream>>>(psum, psq, gamma, beta, scale, shift);
    k_bnselu<<<NODES / 4, 256, 0, stream>>>(outb, scale, shift, yw, yb, yv);
    k_topk<<<8, 512, 0, stream>>>(yv, svals, sidx);
    k_gather<<<(8 * 512) / 4, 256, 0, stream>>>(outb, svals, sidx, out);
}

// Round 16
// 258.095 us; speedup vs baseline: 1.1422x; 1.1234x over previous
//
#include <hip/hip_runtime.h>
#include <math.h>

#define NODES 8192
#define NEDGE 262144
#define DIM 256

typedef float f32x16 __attribute__((ext_vector_type(16)));
typedef _Float16 f16x8 __attribute__((ext_vector_type(8)));
typedef __fp16 h16x2 __attribute__((ext_vector_type(2)));
typedef unsigned short u16;
typedef u16 u16x8 __attribute__((ext_vector_type(8)));
typedef u16 u16x4 __attribute__((ext_vector_type(4)));

__device__ __forceinline__ float fast_tanh(float x) {
    float t = __expf(2.f * x);
    return 1.f - 2.f * __builtin_amdgcn_rcpf(t + 1.f);
}

__device__ __forceinline__ u16 h_bits(_Float16 h) {
    u16 r; __builtin_memcpy(&r, &h, 2); return r;
}

union SplitU { h16x2 h2[2]; u16x4 u4; };

// 2-plane fp16 split of 4 floats via packed RTZ converts (plane2 pre-scaled 2^11)
__device__ __forceinline__ void split4(float p0, float p1, float p2, float p3,
                                       u16x4& v1, u16x4& v2) {
    h16x2 h01 = __builtin_amdgcn_cvt_pkrtz(p0, p1);
    h16x2 h23 = __builtin_amdgcn_cvt_pkrtz(p2, p3);
    h16x2 r01 = __builtin_amdgcn_cvt_pkrtz((p0 - (float)h01[0]) * 2048.f,
                                           (p1 - (float)h01[1]) * 2048.f);
    h16x2 r23 = __builtin_amdgcn_cvt_pkrtz((p2 - (float)h23[0]) * 2048.f,
                                           (p3 - (float)h23[1]) * 2048.f);
    SplitU c1, c2;
    c1.h2[0] = h01; c1.h2[1] = h23;
    c2.h2[0] = r01; c2.h2[1] = r23;
    v1 = c1.u4; v2 = c2.u4;
}

// ---------------- CSR build (dst-indexed) ----------------
__global__ void k_deg(const int* __restrict__ dst, int* __restrict__ deg) {
    int e = blockIdx.x * blockDim.x + threadIdx.x;
    if (e < NEDGE) atomicAdd(&deg[dst[e]], 1);
}

__global__ void k_scan(const int* __restrict__ deg, int* __restrict__ rowptr,
                       int* __restrict__ cursor) {
    __shared__ int part[256];
    int t = threadIdx.x;
    int base = t * 32;
    int local[32];
    int s = 0;
    for (int i = 0; i < 32; ++i) { local[i] = s; s += deg[base + i]; }
    part[t] = s;
    __syncthreads();
    for (int off = 1; off < 256; off <<= 1) {
        int v = (t >= off) ? part[t - off] : 0;
        __syncthreads();
        part[t] += v;
        __syncthreads();
    }
    int excl = (t == 0) ? 0 : part[t - 1];
    for (int i = 0; i < 32; ++i) {
        int v = excl + local[i];
        rowptr[base + i] = v;
        cursor[base + i] = v;
    }
    if (t == 255) rowptr[NODES] = part[255];
}

__global__ void k_fill(const int* __restrict__ src, const int* __restrict__ dst,
                       int* __restrict__ cursor, int2* __restrict__ sdg) {
    int e = blockIdx.x * blockDim.x + threadIdx.x;
    if (e < NEDGE) {
        int pos = atomicAdd(&cursor[dst[e]], 1);
        sdg[pos] = make_int2(src[e], dst[e]);
    }
}

// ------- merged weight fragmentizer: att_w -> wf ; [pwa;pwo] -> wf2 --------
__global__ void k_wfrag_all(const float* __restrict__ W, const float* __restrict__ Wa,
                            const float* __restrict__ Wo, u16* __restrict__ wf,
                            u16* __restrict__ wf2) {
    int t = blockIdx.x * blockDim.x + threadIdx.x;
    const float* S;
    u16* D;
    int gks, w, mt, lane;
    if (t < 8192) {
        lane = t & 63; mt = (t >> 6) & 1; w = (t >> 7) & 3; gks = t >> 9;   // 0..15
        S = W; D = wf;
    } else {
        int t2 = t - 8192;
        if (t2 >= 16384) return;
        lane = t2 & 63; mt = (t2 >> 6) & 1; w = (t2 >> 7) & 3; gks = t2 >> 9; // 0..31
        S = (gks < 16) ? Wa : Wo; D = wf2;
    }
    int row = w * 64 + mt * 32 + (lane & 31);
    int k0 = (gks & 15) * 16 + (lane >> 5) * 8;
    const float* p = S + (size_t)row * DIM + k0;
    u16x8 v1, v2;
#pragma unroll
    for (int j = 0; j < 8; ++j) {
        float f = p[j];
        _Float16 h1 = (_Float16)f;
        _Float16 h2 = (_Float16)((f - (float)h1) * 2048.f);
        v1[j] = h_bits(h1);
        v2[j] = h_bits(h2);
    }
    size_t base = ((size_t)(gks * 4 + w) * 4 + mt * 2) * 512 + lane * 8;
    *(u16x8*)(D + base)       = v1;
    *(u16x8*)(D + base + 512) = v2;
}

// ---------------- alpha, v15: v12 structure + packed-RTZ staging ------------
__global__ __launch_bounds__(256, 2) void k_alpha_v15(
    const float* __restrict__ x, const int2* __restrict__ sdg,
    const u16* __restrict__ wf, const float* __restrict__ bias,
    const float* __restrict__ amap, float* __restrict__ alpha_pos)
{
    __shared__ u16 p_lds[2][64][256];   // 64 KB; [plane][edge][k], byte ^ ((edge&7)<<4)
    const int tid = threadIdx.x;
    const int w = tid >> 6;
    const int lane = tid & 63;
    const int l31 = lane & 31;
    const int g2 = lane >> 5;
    const int bid = blockIdx.x;
    const int wg = (bid & 7) * 512 + (bid >> 3);   // XCD swizzle (4096%8==0)
    const int e0 = wg * 64;
    const int ebase = e0 + w * 16;
    const unsigned swz = ((unsigned)(l31 & 7)) << 4;

    f32x16 accM[2][2], accC[2][2];
#pragma unroll
    for (int mt = 0; mt < 2; ++mt)
#pragma unroll
        for (int nt = 0; nt < 2; ++nt) { accM[mt][nt] = (f32x16)0.f; accC[mt][nt] = (f32x16)0.f; }

    f16x8 afA[2][2], afB[2][2], afC[2][2];

#define PREFA(DST, GKS) { \
    const u16* pb_ = wf + ((size_t)((GKS) * 4 + w) * 4) * 512 + lane * 8; \
    _Pragma("unroll") for (int mt_ = 0; mt_ < 2; ++mt_) \
    _Pragma("unroll") for (int pl_ = 0; pl_ < 2; ++pl_) \
        DST[mt_][pl_] = *(const f16x8*)(const void*)(pb_ + (mt_ * 2 + pl_) * 512); }

#define KS(GKS, USE, PF) { \
    if ((GKS) + 2 < 16) { PREFA(PF, (GKS) + 2) } \
    f16x8 bfr[2][2]; \
    _Pragma("unroll") for (int nt_ = 0; nt_ < 2; ++nt_) { \
        const int en_ = nt_ * 32 + l31; \
        const unsigned off_ = ((unsigned)((GKS) * 32 + g2 * 16)) ^ swz; \
        _Pragma("unroll") for (int pl_ = 0; pl_ < 2; ++pl_) \
            bfr[nt_][pl_] = *(const f16x8*)(const void*)((const char*)&p_lds[pl_][en_][0] + off_); \
    } \
    _Pragma("unroll") for (int mt_ = 0; mt_ < 2; ++mt_) \
    _Pragma("unroll") for (int nt_ = 0; nt_ < 2; ++nt_) { \
        accM[mt_][nt_] = __builtin_amdgcn_mfma_f32_32x32x16_f16(USE[mt_][0], bfr[nt_][0], accM[mt_][nt_], 0, 0, 0); \
        accC[mt_][nt_] = __builtin_amdgcn_mfma_f32_32x32x16_f16(USE[mt_][0], bfr[nt_][1], accC[mt_][nt_], 0, 0, 0); \
        accC[mt_][nt_] = __builtin_amdgcn_mfma_f32_32x32x16_f16(USE[mt_][1], bfr[nt_][0], accC[mt_][nt_], 0, 0, 0); } }

    PREFA(afA, 0)
    PREFA(afB, 1)

    // ---- cooperative staging: wave w stages edges [16w, 16w+16), full K ----
#pragma unroll
    for (int i = 0; i < 16; ++i) {
        int2 sd = sdg[ebase + i];
        float4 a = *(const float4*)(x + (size_t)sd.x * DIM + lane * 4);
        float4 b = *(const float4*)(x + (size_t)sd.y * DIM + lane * 4);
        u16x4 v1, v2;
        split4(a.x * b.x, a.y * b.y, a.z * b.z, a.w * b.w, v1, v2);
        const int le = w * 16 + i;
        const unsigned off = ((unsigned)(lane * 8)) ^ (((unsigned)(le & 7)) << 4);
        *(u16x4*)((char*)&p_lds[0][le][0] + off) = v1;
        *(u16x4*)((char*)&p_lds[1][le][0] + off) = v2;
    }
    __syncthreads();

    // ---- 16-step MFMA burst, A prefetched 2 steps ahead ----
    KS(0,  afA, afC) KS(1,  afB, afA) KS(2,  afC, afB)
    KS(3,  afA, afC) KS(4,  afB, afA) KS(5,  afC, afB)
    KS(6,  afA, afC) KS(7,  afB, afA) KS(8,  afC, afB)
    KS(9,  afA, afC) KS(10, afB, afA) KS(11, afC, afB)
    KS(12, afA, afC) KS(13, afB, afA) KS(14, afC, afB)
    KS(15, afA, afC)
#undef KS
#undef PREFA

    // ---- epilogue: alpha = sum_out amap*tanh(h+bias), h = M + C*2^-11 ----
    float part[2] = {0.f, 0.f};
#pragma unroll
    for (int mt = 0; mt < 2; ++mt)
#pragma unroll
        for (int r = 0; r < 16; ++r) {
            int o = 64 * w + 32 * mt + (r & 3) + 8 * (r >> 2) + 4 * g2;
            float bo = bias[o], ao = amap[o];
#pragma unroll
            for (int nt = 0; nt < 2; ++nt) {
                float h = accM[mt][nt][r] + accC[mt][nt][r] * 4.8828125e-4f;
                part[nt] += ao * fast_tanh(h + bo);
            }
        }
    __syncthreads();
    float* red = (float*)(void*)p_lds;
#pragma unroll
    for (int nt = 0; nt < 2; ++nt) {
        float p = part[nt];
        p += __shfl_xor(p, 32);
        if (lane < 32) red[w * 64 + nt * 32 + lane] = p;
    }
    __syncthreads();
    if (tid < 64) alpha_pos[e0 + tid] = red[tid] + red[64 + tid] + red[128 + tid] + red[192 + tid];
}

// ---------------- segment softmax + weighted aggregate (unroll-4) ----------
__global__ void k_aggregate(
    const float* __restrict__ x, const float* __restrict__ alpha_pos,
    const int* __restrict__ rowptr, const int2* __restrict__ sdg,
    float* __restrict__ agg)
{
    int gw = (blockIdx.x * blockDim.x + threadIdx.x) >> 6;
    int lane = threadIdx.x & 63;
    if (gw >= NODES) return;
    int start = rowptr[gw], end = rowptr[gw + 1];
    int deg = end - start;
    float m = -INFINITY;
    for (int i = lane; i < deg; i += 64) m = fmaxf(m, alpha_pos[start + i]);
#pragma unroll
    for (int off = 32; off > 0; off >>= 1) m = fmaxf(m, __shfl_xor(m, off));
    float ssum = 0.f;
    for (int i = lane; i < deg; i += 64) ssum += expf(alpha_pos[start + i] - m);
#pragma unroll
    for (int off = 32; off > 0; off >>= 1) ssum += __shfl_xor(ssum, off);
    float a0 = 0.f, a1 = 0.f, a2 = 0.f, a3 = 0.f;
    int i = 0;
    for (; i + 4 <= deg; i += 4) {
        float w0 = expf(alpha_pos[start + i]     - m);
        float w1 = expf(alpha_pos[start + i + 1] - m);
        float w2 = expf(alpha_pos[start + i + 2] - m);
        float w3 = expf(alpha_pos[start + i + 3] - m);
        int r0 = sdg[start + i].x;
        int r1 = sdg[start + i + 1].x;
        int r2 = sdg[start + i + 2].x;
        int r3 = sdg[start + i + 3].x;
        float4 v0 = *(const float4*)(x + (size_t)r0 * DIM + lane * 4);
        float4 v1 = *(const float4*)(x + (size_t)r1 * DIM + lane * 4);
        float4 v2 = *(const float4*)(x + (size_t)r2 * DIM + lane * 4);
        float4 v3 = *(const float4*)(x + (size_t)r3 * DIM + lane * 4);
        a0 += w0 * v0.x + w1 * v1.x + w2 * v2.x + w3 * v3.x;
        a1 += w0 * v0.y + w1 * v1.y + w2 * v2.y + w3 * v3.y;
        a2 += w0 * v0.z + w1 * v1.z + w2 * v2.z + w3 * v3.z;
        a3 += w0 * v0.w + w1 * v1.w + w2 * v2.w + w3 * v3.w;
    }
    for (; i < deg; ++i) {
        float wgt = expf(alpha_pos[start + i] - m);
        int r = sdg[start + i].x;
        const float4 v = *(const float4*)(x + (size_t)r * DIM + lane * 4);
        a0 += wgt * v.x; a1 += wgt * v.y; a2 += wgt * v.z; a3 += wgt * v.w;
    }
    float inv = 1.f / (ssum + 1e-16f);
    float4 r; r.x = a0 * inv; r.y = a1 * inv; r.z = a2 * inv; r.w = a3 * inv;
    *(float4*)(agg + (size_t)gw * DIM + lane * 4) = r;
}

// -------- out = [agg|x] @ [Wa;Wo]^T + biases, MFMA 2-split + col-stats ------
__global__ __launch_bounds__(256, 2) void k_out_mfma(
    const float* __restrict__ agg, const float* __restrict__ x,
    const u16* __restrict__ wf2, const float* __restrict__ ba,
    const float* __restrict__ bo, float* __restrict__ outb,
    float* __restrict__ psumf, float* __restrict__ psqf)
{
    __shared__ u16 p_lds[2][64][256];       // 64 KB; reused as float Cs / stat buf
    const int tid = threadIdx.x;
    const int w = tid >> 6;
    const int lane = tid & 63;
    const int l31 = lane & 31;
    const int g2 = lane >> 5;
    const int n0 = blockIdx.x * 64;
    const unsigned swz = ((unsigned)(l31 & 7)) << 4;

    f32x16 accM[2][2], accC[2][2];
#pragma unroll
    for (int mt = 0; mt < 2; ++mt)
#pragma unroll
        for (int nt = 0; nt < 2; ++nt) { accM[mt][nt] = (f32x16)0.f; accC[mt][nt] = (f32x16)0.f; }

    f16x8 afA[2][2], afB[2][2];

#define PREFA2(DST, GKS) { \
    const u16* pb_ = wf2 + ((size_t)((GKS) * 4 + w) * 4) * 512 + lane * 8; \
    _Pragma("unroll") for (int mt_ = 0; mt_ < 2; ++mt_) \
    _Pragma("unroll") for (int pl_ = 0; pl_ < 2; ++pl_) \
        DST[mt_][pl_] = *(const f16x8*)(const void*)(pb_ + (mt_ * 2 + pl_) * 512); }

#define OSTAGE(SRC) { \
    _Pragma("unroll") for (int i_ = 0; i_ < 16; ++i_) { \
        const int ln_ = w * 16 + i_; \
        float4 v_ = *(const float4*)((SRC) + (size_t)(n0 + ln_) * DIM + lane * 4); \
        u16x4 v1_, v2_; \
        split4(v_.x, v_.y, v_.z, v_.w, v1_, v2_); \
        const unsigned off_ = ((unsigned)(lane * 8)) ^ (((unsigned)(ln_ & 7)) << 4); \
        *(u16x4*)((char*)&p_lds[0][ln_][0] + off_) = v1_; \
        *(u16x4*)((char*)&p_lds[1][ln_][0] + off_) = v2_; } }

#define OKSTEP(GKS) { \
    if ((GKS) + 1 < 32) { \
        if ((GKS) & 1) { PREFA2(afA, (GKS) + 1) } else { PREFA2(afB, (GKS) + 1) } \
    } \
    f16x8 bfr[2][2]; \
    _Pragma("unroll") for (int nt_ = 0; nt_ < 2; ++nt_) { \
        const int en_ = nt_ * 32 + l31; \
        const unsigned off_ = ((unsigned)(((GKS) & 15) * 32 + g2 * 16)) ^ swz; \
        _Pragma("unroll") for (int pl_ = 0; pl_ < 2; ++pl_) \
            bfr[nt_][pl_] = *(const f16x8*)(const void*)((const char*)&p_lds[pl_][en_][0] + off_); \
    } \
    _Pragma("unroll") for (int mt_ = 0; mt_ < 2; ++mt_) \
    _Pragma("unroll") for (int nt_ = 0; nt_ < 2; ++nt_) { \
        f16x8 a1_ = ((GKS) & 1) ? afB[mt_][0] : afA[mt_][0]; \
        f16x8 a2_ = ((GKS) & 1) ? afB[mt_][1] : afA[mt_][1]; \
        accM[mt_][nt_] = __builtin_amdgcn_mfma_f32_32x32x16_f16(a1_, bfr[nt_][0], accM[mt_][nt_], 0, 0, 0); \
        accC[mt_][nt_] = __builtin_amdgcn_mfma_f32_32x32x16_f16(a1_, bfr[nt_][1], accC[mt_][nt_], 0, 0, 0); \
        accC[mt_][nt_] = __builtin_amdgcn_mfma_f32_32x32x16_f16(a2_, bfr[nt_][0], accC[mt_][nt_], 0, 0, 0); } }

    PREFA2(afA, 0)
    OSTAGE(agg)
    __syncthreads();
    OKSTEP(0)  OKSTEP(1)  OKSTEP(2)  OKSTEP(3)
    OKSTEP(4)  OKSTEP(5)  OKSTEP(6)  OKSTEP(7)
    OKSTEP(8)  OKSTEP(9)  OKSTEP(10) OKSTEP(11)
    OKSTEP(12) OKSTEP(13) OKSTEP(14) OKSTEP(15)
    __syncthreads();
    OSTAGE(x)
    __syncthreads();
    OKSTEP(16) OKSTEP(17) OKSTEP(18) OKSTEP(19)
    OKSTEP(20) OKSTEP(21) OKSTEP(22) OKSTEP(23)
    OKSTEP(24) OKSTEP(25) OKSTEP(26) OKSTEP(27)
    OKSTEP(28) OKSTEP(29) OKSTEP(30) OKSTEP(31)
#undef OSTAGE
#undef OKSTEP
#undef PREFA2

    // ---- epilogue: bias add + LDS transpose + coalesced store + stats ----
    __syncthreads();
    float* Cs = (float*)(void*)p_lds;       // logical [64 nodes][256 outs], swizzled
#pragma unroll
    for (int mt = 0; mt < 2; ++mt)
#pragma unroll
        for (int r = 0; r < 16; ++r) {
            int o = 64 * w + 32 * mt + (r & 3) + 8 * (r >> 2) + 4 * g2;
            float bs = ba[o] + bo[o];
#pragma unroll
            for (int nt = 0; nt < 2; ++nt) {
                int col = nt * 32 + l31;
                float hv = accM[mt][nt][r] + accC[mt][nt][r] * 4.8828125e-4f + bs;
                unsigned ob = ((unsigned)(col * 1024 + o * 4)) ^ (((unsigned)(col & 31)) << 4);
                *(float*)((char*)Cs + ob) = hv;
            }
        }
    __syncthreads();
    float s4[4] = {0.f, 0.f, 0.f, 0.f};
    float q4[4] = {0.f, 0.f, 0.f, 0.f};
#pragma unroll
    for (int i = 0; i < 16; ++i) {
        int ln = w * 16 + i;
        unsigned rb = ((unsigned)(ln * 1024 + lane * 16)) ^ (((unsigned)(ln & 31)) << 4);
        float4 val = *(const float4*)((const char*)Cs + rb);
        *(float4*)(outb + (size_t)(n0 + ln) * DIM + lane * 4) = val;
        s4[0] += val.x; s4[1] += val.y; s4[2] += val.z; s4[3] += val.w;
        q4[0] += val.x * val.x; q4[1] += val.y * val.y;
        q4[2] += val.z * val.z; q4[3] += val.w * val.w;
    }
    __syncthreads();
    float* rs = (float*)(void*)p_lds;       // [4][256] sums, then [4][256] sq
#pragma unroll
    for (int j = 0; j < 4; ++j) {
        rs[w * 256 + lane * 4 + j] = s4[j];
        rs[1024 + w * 256 + lane * 4 + j] = q4[j];
    }
    __syncthreads();
    if (tid < 256) {
        int c = tid;
        float ssum = rs[c] + rs[256 + c] + rs[512 + c] + rs[768 + c];
        float qsum = rs[1024 + c] + rs[1280 + c] + rs[1536 + c] + rs[1792 + c];
        psumf[blockIdx.x * 256 + c] = ssum;
        psqf[blockIdx.x * 256 + c] = qsum;
    }
}

// ---------------- BN params from 128 per-block fp32 partials (fp64 sum) -----
__global__ void k_bnparam(const float* __restrict__ psumf, const float* __restrict__ psqf,
                          const float* __restrict__ gamma, const float* __restrict__ beta,
                          float* __restrict__ scale, float* __restrict__ shift) {
    int t = threadIdx.x;
    double s = 0.0, q = 0.0;
    for (int g = 0; g < 128; ++g) { s += (double)psumf[g * DIM + t]; q += (double)psqf[g * DIM + t]; }
    double mean = s / (double)NODES;
    double var = q / (double)NODES - mean * mean;
    float sc = (float)((double)gamma[t] / sqrt(var + 1e-5));
    scale[t] = sc;
    shift[t] = (float)((double)beta[t] - mean * (double)sc);
}

// ---------------- affine + SELU + pooling score ----------------
__global__ void k_bnselu(float* __restrict__ outb, const float* __restrict__ scale,
                         const float* __restrict__ shift, const float* __restrict__ yw,
                         const float* __restrict__ yb, float* __restrict__ y) {
    int gw = (blockIdx.x * blockDim.x + threadIdx.x) >> 6;
    int lane = threadIdx.x & 63;
    if (gw >= NODES) return;
    float4 v  = *(const float4*)(outb + (size_t)gw * DIM + lane * 4);
    float4 sc = *(const float4*)(scale + lane * 4);
    float4 sh = *(const float4*)(shift + lane * 4);
    const float SL = 1.0507009873554805f, SA = 1.6732632423543772f;
    float4 o;
    o.x = v.x * sc.x + sh.x;
    o.y = v.y * sc.y + sh.y;
    o.z = v.z * sc.z + sh.z;
    o.w = v.w * sc.w + sh.w;
    o.x = (o.x > 0.f) ? SL * o.x : SL * SA * expm1f(o.x);
    o.y = (o.y > 0.f) ? SL * o.y : SL * SA * expm1f(o.y);
    o.z = (o.z > 0.f) ? SL * o.z : SL * SA * expm1f(o.z);
    o.w = (o.w > 0.f) ? SL * o.w : SL * SA * expm1f(o.w);
    *(float4*)(outb + (size_t)gw * DIM + lane * 4) = o;
    float4 w = *(const float4*)(yw + lane * 4);
    float z = o.x * w.x + o.y * w.y + o.z * w.z + o.w * w.w;
#pragma unroll
    for (int off = 32; off > 0; off >>= 1) z += __shfl_xor(z, off);
    if (lane == 0) y[gw] = 1.f / (1.f + expf(-(z + yb[0])));
}

// ---------------- per-batch bitonic top-k (val desc, idx asc) ----------------
__global__ void k_topk(const float* __restrict__ y, float* __restrict__ svals,
                       int* __restrict__ sidx) {
    __shared__ float v[1024];
    __shared__ int  id[1024];
    int b = blockIdx.x, t = threadIdx.x;   // 512 threads
    v[t] = y[b * 1024 + t];           id[t] = t;
    v[t + 512] = y[b * 1024 + t + 512]; id[t + 512] = t + 512;
    __syncthreads();
    for (int k = 2; k <= 1024; k <<= 1) {
        for (int j = k >> 1; j > 0; j >>= 1) {
            for (int i = t; i < 1024; i += 512) {
                int l = i ^ j;
                if (l > i) {
                    float vi = v[i], vl = v[l];
                    int ii = id[i], il = id[l];
                    bool precede = (vi > vl) || (vi == vl && ii < il);
                    bool dirDesc = ((i & k) == 0);
                    bool sw = dirDesc ? !precede : precede;
                    if (sw) { v[i] = vl; v[l] = vi; id[i] = il; id[l] = ii; }
                }
            }
            __syncthreads();
        }
    }
    if (t < 512) { svals[b * 512 + t] = v[t]; sidx[b * 512 + t] = id[t]; }
}

// ---------------- gather + gate ----------------
__global__ void k_gather(const float* __restrict__ outb, const float* __restrict__ svals,
                         const int* __restrict__ sidx, float* __restrict__ dout) {
    int gw = (blockIdx.x * blockDim.x + threadIdx.x) >> 6;
    int lane = threadIdx.x & 63;
    int b = gw >> 9, r = gw & 511;
    float val = svals[b * 512 + r];
    int idn = sidx[b * 512 + r];
    float4 vv = *(const float4*)(outb + (size_t)(b * 1024 + idn) * DIM + lane * 4);
    vv.x *= val; vv.y *= val; vv.z *= val; vv.w *= val;
    *(float4*)(dout + (size_t)(b * 512 + r) * DIM + lane * 4) = vv;
}

extern "C" void kernel_launch(void* const* d_in, const int* in_sizes, int n_in,
                              void* d_out, int out_size, void* d_ws, size_t ws_size,
                              hipStream_t stream) {
    const float* x     = (const float*)d_in[0];
    const int* edges   = (const int*)d_in[1];
    const float* att_w = (const float*)d_in[2];
    const float* att_b = (const float*)d_in[3];
    const float* amap  = (const float*)d_in[4];
    const float* pwa_w = (const float*)d_in[5];
    const float* pwa_b = (const float*)d_in[6];
    const float* pwo_w = (const float*)d_in[7];
    const float* pwo_b = (const float*)d_in[8];
    const float* gamma = (const float*)d_in[9];
    const float* beta  = (const float*)d_in[10];
    const float* yw    = (const float*)d_in[11];
    const float* yb    = (const float*)d_in[12];
    float* out = (float*)d_out;
    const int* src = edges;
    const int* dst = edges + NEDGE;

    char* ws = (char*)d_ws;
    size_t off = 0;
    auto alloc = [&](size_t b) { void* p = ws + off; off = (off + b + 255) & ~(size_t)255; return p; };
    float* alpha  = (float*)alloc((size_t)NEDGE * 4);      // CSR-position order
    int2*  sdg    = (int2*)alloc((size_t)NEDGE * 8);       // (src,dst) per CSR position
    float* agg    = (float*)alloc((size_t)NODES * DIM * 4);
    float* outb   = (float*)alloc((size_t)NODES * DIM * 4);
    int*   deg    = (int*)alloc(NODES * 4);
    int*   rowptr = (int*)alloc((NODES + 1) * 4);
    int*   cursor = (int*)alloc(NODES * 4);
    float* psumf  = (float*)alloc(128 * DIM * 4);
    float* psqf   = (float*)alloc(128 * DIM * 4);
    float* scale  = (float*)alloc(DIM * 4);
    float* shift  = (float*)alloc(DIM * 4);
    float* yv     = (float*)alloc(NODES * 4);
    float* svals  = (float*)alloc(8 * 512 * 4);
    int*   sidx   = (int*)alloc(8 * 512 * 4);
    u16*   wf     = (u16*)alloc((size_t)16 * 4 * 4 * 512 * 2);
    u16*   wf2    = (u16*)alloc((size_t)32 * 4 * 4 * 512 * 2);

    (void)hipMemsetAsync(deg, 0, NODES * 4, stream);
    k_wfrag_all<<<96, 256, 0, stream>>>(att_w, pwa_w, pwo_w, wf, wf2);
    k_deg<<<NEDGE / 256, 256, 0, stream>>>(dst, deg);
    k_scan<<<1, 256, 0, stream>>>(deg, rowptr, cursor);
    k_fill<<<NEDGE / 256, 256, 0, stream>>>(src, dst, cursor, sdg);
    k_alpha_v15<<<NEDGE / 64, 256, 0, stream>>>(x, sdg, wf, att_b, amap, alpha);
    k_aggregate<<<NODES / 4, 256, 0, stream>>>(x, alpha, rowptr, sdg, agg);
    k_out_mfma<<<NODES / 64, 256, 0, stream>>>(agg, x, wf2, pwa_b, pwo_b, outb, psumf, psqf);
    k_bnparam<<<1, 256, 0, stream>>>(psumf, psqf, gamma, beta, scale, shift);
    k_bnselu<<<NODES / 4, 256, 0, stream>>>(outb, scale, shift, yw, yb, yv);
    k_topk<<<8, 512, 0, stream>>>(yv, svals, sidx);
    k_gather<<<(8 * 512) / 4, 256, 0, stream>>>(outb, svals, sidx, out);
}